// Round 4
// baseline (150.616 us; speedup 1.0000x reference)
//
#include <hip/hip_runtime.h>
#include <stdint.h>

// Q2Linear int8 path, 2 dispatches — R15: 64x64 tiles -> 1024 blocks = 4/CU (TLP).
//   prep: unchanged (quantize x -> i8; pack w int32 -> i8). ~17us, at BW floor.
//   q8_gemm: i8 MFMA 32x32x32, tile 64m x 64n, BK=128, 1024 blocks.
//     Diagnosis chain: R13 counters showed all pipes <20% at Occupancy 18.7% --
//     grid-capped at 2 blocks/CU (512 blocks). R14 (ILP depth) null -> the lever
//     is TLP. This round: half the n-tile -> 4 blocks/CU resident. LDS 32 KB/blk
//     (A 64x128 + B 64x128, dbuf; B tile now shaped exactly like A). Scales leave
//     LDS (R14 proved direct-L2 scale reads free): register-prefetched 1 slab
//     ahead (sfA/sfB named, rule #20). Each wave owns a 32x32 quadrant
//     (wm=wave>>1, wn2=wave&1): 1 MFMA per kp, fac 16 regs -> VGPR ~56 under the
//     __launch_bounds__(256,4) cap of 128. 2-barrier dbuf loop kept verbatim from
//     R12 (one variable changed: occupancy).
// Fragment maps: A/B row = lane&31, k-chunk = lane>>5; C/D col = lane&31,
// row = (reg&3) + 8*(reg>>2) + 4*(lane>>5).
// Ledger: R8 -36%; R9 64x64/4-blk VGPR-balloon -2.7x (this round avoids: quadrant
// waves keep VGPR ~56); R10 direct-A -2x; R11=R7 143.0; R12 32x32+setprio 144.1
// (null -> not issue-bound); R13 direct-B 151.9 (latency-bound diagnosis);
// R14 counted-vmcnt 3-buf 146.2 (ILP-depth null -> TLP this round).
// Timed region: ~83us harness fills + prep ~17 + gemm ~41 (target ~29).

#define MM 1024
#define NN 4096
#define KK 4096
#define BK 128

typedef __attribute__((ext_vector_type(4))) int intx4;
typedef __attribute__((ext_vector_type(16))) int intx16;
typedef __attribute__((ext_vector_type(4))) float floatx4;
typedef __attribute__((ext_vector_type(16))) float floatx16;

typedef const __attribute__((address_space(1))) void global_cvoid;
typedef __attribute__((address_space(3))) void lds_void;

// ---- prep: quantize x (blocks < MM) OR pack w -> i8 --------------------------
__global__ __launch_bounds__(256) void prep(const float* __restrict__ x,
                                            const int* __restrict__ wq,
                                            char* __restrict__ xq,
                                            float* __restrict__ qrow,
                                            char* __restrict__ wb) {
    const int tid = threadIdx.x;
    if (blockIdx.x < MM) {
        const int m = blockIdx.x;
        const float* xr = x + (size_t)m * KK;
        floatx4 v[4];
        float amax = 0.f;
#pragma unroll
        for (int c = 0; c < 4; ++c) {
            v[c] = *(const floatx4*)(xr + (c * 256 + tid) * 4);
#pragma unroll
            for (int e = 0; e < 4; ++e) amax = fmaxf(amax, fabsf(v[c][e]));
        }
#pragma unroll
        for (int off = 32; off; off >>= 1) amax = fmaxf(amax, __shfl_down(amax, off));
        __shared__ float wmax[4];
        if ((tid & 63) == 0) wmax[tid >> 6] = amax;
        __syncthreads();
        amax = fmaxf(fmaxf(wmax[0], wmax[1]), fmaxf(wmax[2], wmax[3]));
        amax = fmaxf(amax, 1e-20f);
        const float qinv = 127.0f / amax;
        if (tid == 0) qrow[m] = amax / 127.0f;
#pragma unroll
        for (int c = 0; c < 4; ++c) {
            int p = 0;
#pragma unroll
            for (int e = 0; e < 4; ++e) {
                float r = rintf(v[c][e] * qinv);
                r = fminf(fmaxf(r, -127.f), 127.f);
                p |= ((int)r & 255) << (8 * e);
            }
            *(int*)(xq + (size_t)m * KK + (c * 256 + tid) * 4) = p;
        }
    } else {
        // pack w: fully coalesced (lane-consecutive 16B reads / 4B writes)
        const int blk = blockIdx.x - MM;
#pragma unroll
        for (int c = 0; c < 4; ++c) {
            size_t c4 = (size_t)blk * 1024 + c * 256 + tid;  // intx4-chunk id
            intx4 a = ((const intx4*)wq)[c4];
            ((int*)wb)[c4] = (a[0] & 255) | ((a[1] & 255) << 8) |
                             ((a[2] & 255) << 16) | (a[3] << 24);
        }
    }
}

// ---- GEMM: 64x64 tile, 4 waves (each 32m x 32n quadrant), dbuf LDS -----------
__global__ __launch_bounds__(256, 4) void q8_gemm(const char* __restrict__ xq,
                                                  const char* __restrict__ wb,
                                                  const float* __restrict__ qrow,
                                                  const float* __restrict__ scales,
                                                  float* __restrict__ out) {
    __shared__ char As[2][64 * BK];    // 8 KB each
    __shared__ char Bs[2][64 * BK];    // 8 KB each
    // total 32 KB -> 4 blocks/CU (grid 1024 = 4/CU; LDS would allow 5)

    const int tid  = threadIdx.x;
    const int lane = tid & 63;
    const int wave = tid >> 6;
    const int l31  = lane & 31;        // A/B fragment row, C/D col (n)
    const int hi   = lane >> 5;        // k-chunk half selector
    const int sw   = lane & 7;         // XOR-swizzle key (== row&7 for all reads)
    const int wm   = wave >> 1;        // wave quadrant: m-half
    const int wn2  = wave & 1;         // wave quadrant: n-half

    // XCD pinning: bid&7 -> XCD; each XCD owns 8 n-tiles (512 cols, 2MB B-strip)
    const int bid = blockIdx.x;
    const int xcd = bid & 7, loc = bid >> 3;   // loc 0..127
    const int nT = xcd * 8 + (loc & 7);        // 0..63
    const int mT = loc >> 3;                   // 0..15
    const int mBase = mT * 64, nBase = nT * 64;

    // staging address permute -> XOR-swizzled LDS tile (same geometry as R7/R12;
    // B tile is now 64 rows, staged identically to A)
    const int rg = lane >> 3;
    const int cs = (lane & 7) ^ rg;
    const char* gA = xq + (size_t)(mBase + wave * 16 + rg) * KK + cs * 16;
    const char* gB = wb + (size_t)(nBase + wave * 16 + rg) * KK + cs * 16;
    const int ldsRow = wave * 16;

    // per-lane scale row (this wave's n-column), read direct from L2
    const float* scrow = scales + (size_t)(nBase + wn2 * 32 + l31) * 32;

    floatx16 fac;
#pragma unroll
    for (int r = 0; r < 16; ++r) fac[r] = 0.f;

#define STAGE(BUF, SLAB)                                                        \
    {                                                                           \
        _Pragma("unroll")                                                       \
        for (int t = 0; t < 2; ++t)                                             \
            __builtin_amdgcn_global_load_lds(                                   \
                (global_cvoid*)(gA + (size_t)(t * 8) * KK + (size_t)(SLAB) * BK),\
                (lds_void*)&As[BUF][(ldsRow + t * 8) * BK], 16, 0, 0);          \
        _Pragma("unroll")                                                       \
        for (int t = 0; t < 2; ++t)                                             \
            __builtin_amdgcn_global_load_lds(                                   \
                (global_cvoid*)(gB + (size_t)(t * 8) * KK + (size_t)(SLAB) * BK),\
                (lds_void*)&Bs[BUF][(ldsRow + t * 8) * BK], 16, 0, 0);          \
    }

    // per kp: av row wm*32+l31, bv row wn2*32+l31, k-chunk ((kp*2+hi)^sw).
    // 8 ds_read_b128 + 4 MFMA per slab per wave.
#define COMPUTE(BUF, SF)                                                        \
    {                                                                           \
        intx16 iacc;                                                            \
        __builtin_amdgcn_s_setprio(1);                                          \
        _Pragma("unroll")                                                       \
        for (int kp = 0; kp < 4; ++kp) {                                        \
            const int kc = (((kp * 2) + hi) ^ sw) << 4;                         \
            intx4 av = *(const intx4*)&As[BUF][(wm * 32 + l31) * BK + kc];      \
            intx4 bv = *(const intx4*)&Bs[BUF][(wn2 * 32 + l31) * BK + kc];     \
            if (kp == 0) {                                                      \
                intx16 z = {0, 0, 0, 0, 0, 0, 0, 0, 0, 0, 0, 0, 0, 0, 0, 0};    \
                iacc = __builtin_amdgcn_mfma_i32_32x32x32_i8(av, bv, z, 0, 0, 0); \
            } else {                                                            \
                iacc = __builtin_amdgcn_mfma_i32_32x32x32_i8(av, bv, iacc, 0, 0, 0); \
            }                                                                   \
        }                                                                       \
        __builtin_amdgcn_s_setprio(0);                                          \
        _Pragma("unroll")                                                       \
        for (int r = 0; r < 16; ++r) fac[r] += (float)iacc[r] * (SF);           \
    }

    float sfA = scrow[0], sfB;
    STAGE(0, 0)
    __syncthreads();

    const int NIT = KK / BK;  // 32
    for (int it = 0; it < NIT; it += 2) {
        if (it + 1 < NIT) { STAGE(1, it + 1) sfB = scrow[it + 1]; }
        COMPUTE(0, sfA)
        __syncthreads();
        if (it + 2 < NIT) { STAGE(0, it + 2) sfA = scrow[it + 2]; }
        COMPUTE(1, sfB)
        __syncthreads();
    }

    // epilogue: C/D col = lane&31 (n), row = (reg&3)+8*(reg>>2)+4*hi (m); fold q[m]
#pragma unroll
    for (int g = 0; g < 4; ++g) {
        floatx4 qv = *(const floatx4*)(qrow + mBase + wm * 32 + g * 8 + hi * 4);
#pragma unroll
        for (int r = 0; r < 4; ++r) {
            const int m0 = mBase + wm * 32 + g * 8 + hi * 4 + r;
            out[(size_t)m0 * NN + nBase + wn2 * 32 + l31] = fac[g * 4 + r] * qv[r];
        }
    }
#undef STAGE
#undef COMPUTE
}

extern "C" void kernel_launch(void* const* d_in, const int* in_sizes, int n_in,
                              void* d_out, int out_size, void* d_ws, size_t ws_size,
                              hipStream_t stream) {
    const float* x      = (const float*)d_in[0];
    const int*   wq     = (const int*)d_in[1];
    const float* scales = (const float*)d_in[2];
    float*       out    = (float*)d_out;

    char*  xq   = (char*)d_ws;                                   // 4 MB
    float* qrow = (float*)((char*)d_ws + (size_t)MM * KK);       // 4 KB
    char*  wb   = (char*)d_ws + (size_t)MM * KK + 4096;          // 16.8 MB

    prep<<<MM + (size_t)NN * KK / 16 / 256, 256, 0, stream>>>(x, wq, xq, qrow, wb);
    q8_gemm<<<(MM / 64) * (NN / 64), 256, 0, stream>>>(xq, wb, qrow, scales, out);
}